// Round 3
// baseline (355.389 us; speedup 1.0000x reference)
//
#include <hip/hip_runtime.h>
#include <math.h>

#define N_NODES 50000
#define N_EDGES 1600000
#define BT 48           // B*T columns
#define CTILE 16        // columns per spmm pass (slab = 50000*16*4 = 3.2 MB, L2-resident)
#define NPASS 3
#define MAXCAP 80       // ELL capacity; degree ~ Poisson(32)
#define CNTS 16         // cnt padding stride (1 counter per 64B line)

// ---------------- init: cnt = 0 (padded) ----------------
__global__ __launch_bounds__(256) void init_k(int* __restrict__ cnt) {
  int n = blockIdx.x * 256 + threadIdx.x;
  if (n < N_NODES * CNTS) cnt[n] = 0;
}

// ---------------- ELL build: one atomic + one packed 8B store per edge ----------------
__global__ __launch_bounds__(256) void fill_k(const int* __restrict__ ei,
                                              const float* __restrict__ ew,
                                              int* __restrict__ cnt,
                                              int2* __restrict__ ell,
                                              int cap) {
  int e0 = 2 * (blockIdx.x * 256 + threadIdx.x);
  if (e0 >= N_EDGES) return;
  int2   s2 = *(const int2*)(ei + e0);             // srcs (row 0)
  int2   d2 = *(const int2*)(ei + N_EDGES + e0);   // dsts (row 1)
  float2 w2 = *(const float2*)(ew + e0);

  int slot0 = atomicAdd(&cnt[(size_t)d2.x * CNTS], 1);
  int slot1 = atomicAdd(&cnt[(size_t)d2.y * CNTS], 1);
  if (slot0 < cap) ell[(size_t)d2.x * cap + slot0] = make_int2(s2.x, __float_as_int(w2.x));
  if (slot1 < cap) ell[(size_t)d2.y * cap + slot1] = make_int2(s2.y, __float_as_int(w2.y));
}

// ---------------- deg from ELL row, dinv = (1+sum_w)^-0.5 ; wave per node ----------------
__global__ __launch_bounds__(256) void deg_k(const int2* __restrict__ ell,
                                             const int* __restrict__ cnt,
                                             float* __restrict__ dinv,
                                             int cap) {
  int lane = threadIdx.x & 63;
  int n = (blockIdx.x * 256 + threadIdx.x) >> 6;
  if (n >= N_NODES) return;
  int c = cnt[(size_t)n * CNTS];
  if (c > cap) c = cap;
  const int2* row = ell + (size_t)n * cap;
  float s = 0.0f;
  for (int i = lane; i < c; i += 64) s += __int_as_float(row[i].y);
#pragma unroll
  for (int off = 32; off >= 1; off >>= 1) s += __shfl_xor(s, off, 64);
  if (lane == 0) dinv[n] = 1.0f / sqrtf(1.0f + s);
}

// ---- transpose+scale: x_seq [BT,N] -> 3 slabs xs[p][N][16], xs = dinv[n]*x ----
__global__ __launch_bounds__(256) void transpose_k(const float* __restrict__ x,
                                                   const float* __restrict__ dinv,
                                                   float* __restrict__ xs) {
  int n = blockIdx.x * 256 + threadIdx.x;
  if (n >= N_NODES) return;
  float dn = dinv[n];
#pragma unroll
  for (int p = 0; p < NPASS; ++p) {
    float tmp[CTILE];
#pragma unroll
    for (int c = 0; c < CTILE; ++c)
      tmp[c] = dn * x[(size_t)(p * CTILE + c) * N_NODES + n];  // coalesced per c
    float4* dst = (float4*)(xs + ((size_t)p * N_NODES + n) * CTILE);
#pragma unroll
    for (int j = 0; j < CTILE / 4; ++j)
      dst[j] = make_float4(tmp[4 * j], tmp[4 * j + 1], tmp[4 * j + 2], tmp[4 * j + 3]);
  }
}

// ---------------- SpMM pass: wave per node, 4 edges/iter via 16-lane groups ----------------
// agg[n, p*16+c] = dinv[n] * ( sum_e w_e * xs[src_e, c] + xs[n, c] )
__global__ __launch_bounds__(256) void spmm_k(const float* __restrict__ xs_all,
                                              const long* __restrict__ ell,
                                              const int* __restrict__ cnt,
                                              const float* __restrict__ dinv,
                                              float* __restrict__ agg,
                                              int cap, int pass) {
  int lane = threadIdx.x & 63;
  int n = (blockIdx.x * 256 + threadIdx.x) >> 6;
  if (n >= N_NODES) return;
  const float* xs = xs_all + (size_t)pass * N_NODES * CTILE;
  int c = cnt[(size_t)n * CNTS];
  if (c > cap) c = cap;
  int g = lane >> 4, cidx = lane & 15;
  const long* pp = ell + (size_t)n * cap;

  float acc = 0.0f;
  for (int i = 0; i < c; i += 8) {   // 8 edges per iter: 2 per lane-group, masked tail
    int e0 = i + g, e1 = i + 4 + g;
    bool v0 = e0 < c, v1 = e1 < c;
    long m0 = __builtin_nontemporal_load(&pp[v0 ? e0 : 0]);
    long m1 = __builtin_nontemporal_load(&pp[v1 ? e1 : 0]);
    int   s0 = (int)(m0 & 0xffffffffL);
    int   s1 = (int)(m1 & 0xffffffffL);
    float w0 = v0 ? __int_as_float((int)(m0 >> 32)) : 0.0f;
    float w1 = v1 ? __int_as_float((int)(m1 >> 32)) : 0.0f;
    float x0 = xs[(size_t)s0 * CTILE + cidx];   // one aligned 64B line per group (L2 hit)
    float x1 = xs[(size_t)s1 * CTILE + cidx];
    acc = fmaf(w0, x0, acc);
    acc = fmaf(w1, x1, acc);
  }
  // sum the 4 lane-groups
  acc += __shfl_xor(acc, 16, 64);
  acc += __shfl_xor(acc, 32, 64);

  if (lane < 16) {
    float dn = dinv[n];
    float r = dn * (acc + xs[(size_t)n * CTILE + lane]);   // self loop: dn*xs_n = dn^2*x_n
    __builtin_nontemporal_store(r, &agg[(size_t)n * BT + pass * CTILE + lane]);
  }
}

// ---------------- fold conv_w through the (rank-1) GCN weight ----------------
__global__ void coeff_k(const float* __restrict__ conv_w, const float* __restrict__ gcn_w,
                        const float* __restrict__ gcn_b, float* __restrict__ wv,
                        float* __restrict__ wb) {
  int idx = threadIdx.x;
  if (idx >= 96) return;
  int co = idx / 3, k = idx % 3;
  float sv = 0.0f, sb = 0.0f;
  for (int ci = 0; ci < 32; ++ci) {
    float w = conv_w[co * 96 + ci * 3 + k];  // [32,32,3]
    sv += w * gcn_w[ci];                     // gcn_w shape (1,32)
    sb += w * gcn_b[ci];
  }
  wv[idx] = sv;
  wb[idx] = sb;
}

// ---------------- epilogue: conv3 + relu + mean + linear, closed form per (b,n) ----------------
__global__ __launch_bounds__(256) void epi_k(const float* __restrict__ agg,
                                             const float* __restrict__ wv,
                                             const float* __restrict__ wb,
                                             const float* __restrict__ conv_b,
                                             const float* __restrict__ lin_w,
                                             const float* __restrict__ lin_b,
                                             float* __restrict__ out) {
  __shared__ float s_wv[96], s_wb[96], s_cb[32], s_lw[32], s_lb;
  int tid = threadIdx.x;
  if (tid < 96) { s_wv[tid] = wv[tid]; s_wb[tid] = wb[tid]; }
  if (tid < 32) { s_cb[tid] = conv_b[tid]; s_lw[tid] = lin_w[tid]; }
  if (tid == 0) s_lb = lin_b[0];
  __syncthreads();

  int n = blockIdx.x * 256 + tid;
  if (n >= N_NODES) return;
  const float4* ap = (const float4*)(agg + (size_t)n * BT);

#pragma unroll
  for (int b = 0; b < 4; ++b) {
    float4 q0 = ap[b * 3], q1 = ap[b * 3 + 1], q2 = ap[b * 3 + 2];
    float a[14];  // a[0], a[13] are the zero pads; all indices compile-time
    a[0] = 0.0f; a[13] = 0.0f;
    a[1] = q0.x; a[2] = q0.y; a[3] = q0.z; a[4] = q0.w;
    a[5] = q1.x; a[6] = q1.y; a[7] = q1.z; a[8] = q1.w;
    a[9] = q2.x; a[10] = q2.y; a[11] = q2.z; a[12] = q2.w;

    float acc = 0.0f;
    for (int co = 0; co < 32; ++co) {
      float w0 = s_wv[3 * co], w1 = s_wv[3 * co + 1], w2 = s_wv[3 * co + 2];
      float b0 = s_wb[3 * co], b1 = s_wb[3 * co + 1], b2 = s_wb[3 * co + 2];
      float base = s_cb[co] + b1;
      float lw = s_lw[co];
      float sr = 0.0f;
#pragma unroll
      for (int t = 0; t < 12; ++t) {
        float v = base + w0 * a[t] + w1 * a[t + 1] + w2 * a[t + 2];
        if (t > 0)  v += b0;   // bias only where the conv window overlaps valid h
        if (t < 11) v += b2;
        sr += fmaxf(v, 0.0f);
      }
      acc = fmaf(lw, sr, acc);
    }
    out[b * N_NODES + n] = s_lb + acc * (1.0f / 12.0f);
  }
}

extern "C" void kernel_launch(void* const* d_in, const int* in_sizes, int n_in,
                              void* d_out, int out_size, void* d_ws, size_t ws_size,
                              hipStream_t stream) {
  const float* x_seq  = (const float*)d_in[0];
  const int*   ei     = (const int*)d_in[1];   // [2, E] int32 per harness contract
  const float* ew     = (const float*)d_in[2];
  const float* gcn_w  = (const float*)d_in[3];
  const float* gcn_b  = (const float*)d_in[4];
  const float* conv_w = (const float*)d_in[5];
  const float* conv_b = (const float*)d_in[6];
  const float* lin_w  = (const float*)d_in[7];
  const float* lin_b  = (const float*)d_in[8];
  float* out = (float*)d_out;

  char* ws = (char*)d_ws;
  size_t off = 0;
  auto alloc = [&](size_t bytes) -> void* {
    void* p = ws + off;
    off += (bytes + 511) & ~(size_t)511;
    return p;
  };
  float* xs   = (float*)alloc((size_t)NPASS * N_NODES * CTILE * 4);
  float* agg  = (float*)alloc((size_t)N_NODES * BT * 4);
  float* dinv = (float*)alloc((size_t)N_NODES * 4);
  int*   cnt  = (int*)alloc((size_t)N_NODES * CNTS * 4);
  float* wv   = (float*)alloc(96 * 4);
  float* wb   = (float*)alloc(96 * 4);

  // ELL capacity: 80 if scratch allows, else degrade (still correct for cap >= max degree ~65)
  int cap = MAXCAP;
  if (ws_size > off) {
    size_t remain = ws_size - off;
    size_t cap_fit = remain / ((size_t)N_NODES * 8);
    if (cap_fit < (size_t)cap) cap = (int)cap_fit;
  }
  if (cap < 1) cap = 1;
  int2* ell = (int2*)alloc((size_t)N_NODES * cap * 8);

  const int nblk  = (N_NODES + 255) / 256;
  const int cblk  = (N_NODES * CNTS + 255) / 256;
  const int eblk2 = (N_EDGES / 2 + 255) / 256;
  const int wblk  = (N_NODES * 64 + 255) / 256;

  hipLaunchKernelGGL(init_k, dim3(cblk), dim3(256), 0, stream, cnt);
  hipLaunchKernelGGL(fill_k, dim3(eblk2), dim3(256), 0, stream, ei, ew, cnt, ell, cap);
  hipLaunchKernelGGL(deg_k, dim3(wblk), dim3(256), 0, stream, ell, cnt, dinv, cap);
  hipLaunchKernelGGL(transpose_k, dim3(nblk), dim3(256), 0, stream, x_seq, dinv, xs);
  for (int p = 0; p < NPASS; ++p)
    hipLaunchKernelGGL(spmm_k, dim3(wblk), dim3(256), 0, stream,
                       xs, (const long*)ell, cnt, dinv, agg, cap, p);
  hipLaunchKernelGGL(coeff_k, dim3(1), dim3(128), 0, stream, conv_w, gcn_w, gcn_b, wv, wb);
  hipLaunchKernelGGL(epi_k, dim3(nblk), dim3(256), 0, stream, agg, wv, wb, conv_b, lin_w, lin_b, out);
}

// Round 4
// 221.003 us; speedup vs baseline: 1.6081x; 1.6081x over previous
//
#include <hip/hip_runtime.h>
#include <math.h>

#define N_NODES 50000
#define N_EDGES 1600000
#define BT 48            // B*T columns
#define CAP 80           // ELL capacity (degree ~ Poisson(32))
#define BINSZ 64         // nodes per bin
#define NBINS 782        // ceil(50000/64)
#define ECHUNK 8192      // edges per stage block

// ---------------- init: stage counters = 0 ----------------
__global__ __launch_bounds__(1024) void init_k(int* __restrict__ sc) {
  int i = threadIdx.x;
  if (i < NBINS) sc[i] = 0;
}

// ---------------- Phase A: bin edges into per-bin staging (dense appends) ----------------
__global__ __launch_bounds__(256) void stage_k(const int* __restrict__ ei,
                                               const float* __restrict__ ew,
                                               int* __restrict__ stage_cnt,
                                               int2* __restrict__ staged,
                                               int scap) {
  __shared__ int hist[NBINS];
  __shared__ int ptr[NBINS];
  int t = threadIdx.x;
  for (int b = t; b < NBINS; b += 256) hist[b] = 0;
  __syncthreads();

  int e0 = blockIdx.x * ECHUNK;
  int ne = min(ECHUNK, N_EDGES - e0);

  for (int k = t; k < ne; k += 256) {                 // pass 1: histogram (dst only)
    int d = ei[N_EDGES + e0 + k];
    atomicAdd(&hist[d >> 6], 1);
  }
  __syncthreads();
  for (int b = t; b < NBINS; b += 256) {              // reserve contiguous runs
    int h = hist[b];
    ptr[b] = h ? atomicAdd(&stage_cnt[b], h) : 0;
  }
  __syncthreads();
  for (int k = t; k < ne; k += 256) {                 // pass 2: append
    int e = e0 + k;
    int s = ei[e];
    int d = ei[N_EDGES + e];
    float w = ew[e];
    int b = d >> 6;
    int p = atomicAdd(&ptr[b], 1);
    if (p < scap)
      staged[(size_t)b * scap + p] = make_int2(s | ((d & 63) << 16), __float_as_int(w));
  }
}

// ---------------- Phase B: per-bin ELL build in LDS + deg/dinv + dense write-out ----------------
__global__ __launch_bounds__(256) void build_k(const int2* __restrict__ staged,
                                               const int* __restrict__ stage_cnt,
                                               int2* __restrict__ ell,
                                               int* __restrict__ cnt,
                                               float* __restrict__ dinv,
                                               int scap) {
  __shared__ int2 rows[BINSZ][CAP];   // 40 KB
  __shared__ int rcnt[BINSZ];
  int t = threadIdx.x, b = blockIdx.x;
  if (t < BINSZ) rcnt[t] = 0;
  __syncthreads();

  int ne = min(stage_cnt[b], scap);
  const int2* sp = staged + (size_t)b * scap;
  for (int k = t; k < ne; k += 256) {
    int2 m = sp[k];
    int dloc = (m.x >> 16) & 63;
    int src  = m.x & 0xffff;
    int slot = atomicAdd(&rcnt[dloc], 1);
    if (slot < CAP) rows[dloc][slot] = make_int2(src, m.y);
  }
  __syncthreads();

  int base = b * BINSZ;
  if (t < BINSZ) {                                    // deg -> dinv, cnt
    int n = base + t;
    if (n < N_NODES) {
      int c = min(rcnt[t], CAP);
      float s = 0.0f;
      for (int i = 0; i < c; ++i) s += __int_as_float(rows[t][i].y);
      cnt[n] = c;
      dinv[n] = 1.0f / sqrtf(1.0f + s);               // self-loop weight 1
    }
  }
  __syncthreads();

  int r = t & 63, st = t >> 6;                        // 4 threads per row
  int n = base + r;
  if (n < N_NODES) {
    int c = min(rcnt[r], CAP);
    int2* dst = ell + (size_t)n * CAP;
    for (int i = st; i < c; i += 4) dst[i] = rows[r][i];
  }
}

// ---- transpose+scale: x_seq [BT,N] -> xs [N,BT], xs = dinv[n]*x ----
__global__ __launch_bounds__(256) void transpose_k(const float* __restrict__ x,
                                                   const float* __restrict__ dinv,
                                                   float* __restrict__ xs) {
  int n = blockIdx.x * 256 + threadIdx.x;
  if (n >= N_NODES) return;
  float dn = dinv[n];
  float tmp[BT];
#pragma unroll
  for (int bt = 0; bt < BT; ++bt) tmp[bt] = dn * x[(size_t)bt * N_NODES + n];
  float4* dst = (float4*)(xs + (size_t)n * BT);
#pragma unroll
  for (int j = 0; j < BT / 4; ++j)
    dst[j] = make_float4(tmp[4 * j], tmp[4 * j + 1], tmp[4 * j + 2], tmp[4 * j + 3]);
}

// ---------------- SpMM: wave per node, metadata in registers, 8 gathers in flight ----------------
// agg[n,c] = dinv[n] * ( sum_e w_e * xs[src_e, c] + xs[n, c] )
__global__ __launch_bounds__(256) void spmm_k(const float* __restrict__ xs,
                                              const int2* __restrict__ ell,
                                              const int* __restrict__ cnt,
                                              const float* __restrict__ dinv,
                                              float* __restrict__ agg) {
  int lane = threadIdx.x & 63;
  int n = (blockIdx.x * 256 + threadIdx.x) >> 6;
  if (n >= N_NODES) return;
  int col = (lane < BT) ? lane : (BT - 1);            // dup col 47: no extra lines
  const int2* pp = ell + (size_t)n * CAP;
  int c = __builtin_amdgcn_readfirstlane(cnt[n]);
  int2 m = pp[lane];                                  // 64 edges' metadata in one coalesced load
  float acc = 0.0f;
  int cm = (c < 64) ? c : 64;

  int e = 0;
  for (; e + 8 <= cm; e += 8) {                       // broadcast via readlane (register-only)
    int   s0 = __builtin_amdgcn_readlane(m.x, e + 0);
    int   s1 = __builtin_amdgcn_readlane(m.x, e + 1);
    int   s2 = __builtin_amdgcn_readlane(m.x, e + 2);
    int   s3 = __builtin_amdgcn_readlane(m.x, e + 3);
    int   s4 = __builtin_amdgcn_readlane(m.x, e + 4);
    int   s5 = __builtin_amdgcn_readlane(m.x, e + 5);
    int   s6 = __builtin_amdgcn_readlane(m.x, e + 6);
    int   s7 = __builtin_amdgcn_readlane(m.x, e + 7);
    float w0 = __int_as_float(__builtin_amdgcn_readlane(m.y, e + 0));
    float w1 = __int_as_float(__builtin_amdgcn_readlane(m.y, e + 1));
    float w2 = __int_as_float(__builtin_amdgcn_readlane(m.y, e + 2));
    float w3 = __int_as_float(__builtin_amdgcn_readlane(m.y, e + 3));
    float w4 = __int_as_float(__builtin_amdgcn_readlane(m.y, e + 4));
    float w5 = __int_as_float(__builtin_amdgcn_readlane(m.y, e + 5));
    float w6 = __int_as_float(__builtin_amdgcn_readlane(m.y, e + 6));
    float w7 = __int_as_float(__builtin_amdgcn_readlane(m.y, e + 7));
    float x0 = xs[(size_t)s0 * BT + col];
    float x1 = xs[(size_t)s1 * BT + col];
    float x2 = xs[(size_t)s2 * BT + col];
    float x3 = xs[(size_t)s3 * BT + col];
    float x4 = xs[(size_t)s4 * BT + col];
    float x5 = xs[(size_t)s5 * BT + col];
    float x6 = xs[(size_t)s6 * BT + col];
    float x7 = xs[(size_t)s7 * BT + col];
    acc = fmaf(w0, x0, acc); acc = fmaf(w1, x1, acc);
    acc = fmaf(w2, x2, acc); acc = fmaf(w3, x3, acc);
    acc = fmaf(w4, x4, acc); acc = fmaf(w5, x5, acc);
    acc = fmaf(w6, x6, acc); acc = fmaf(w7, x7, acc);
  }
  for (; e < cm; ++e) {
    int   s = __builtin_amdgcn_readlane(m.x, e);
    float w = __int_as_float(__builtin_amdgcn_readlane(m.y, e));
    acc = fmaf(w, xs[(size_t)s * BT + col], acc);
  }
  for (; e < c; ++e) {                                // rare c>64 tail: meta from memory
    int2 q = pp[e];
    int   s = __builtin_amdgcn_readfirstlane(q.x);
    float w = __int_as_float(__builtin_amdgcn_readfirstlane(q.y));
    acc = fmaf(w, xs[(size_t)s * BT + col], acc);
  }

  if (lane < BT) {
    float dn = dinv[n];
    float r = dn * (acc + xs[(size_t)n * BT + col]);  // self loop: dn*xs_n = dn^2*x_n
    __builtin_nontemporal_store(r, &agg[(size_t)n * BT + col]);
  }
}

// ---------------- fold conv_w through the (rank-1) GCN weight ----------------
__global__ void coeff_k(const float* __restrict__ conv_w, const float* __restrict__ gcn_w,
                        const float* __restrict__ gcn_b, float* __restrict__ wv,
                        float* __restrict__ wb) {
  int idx = threadIdx.x;
  if (idx >= 96) return;
  int co = idx / 3, k = idx % 3;
  float sv = 0.0f, sb = 0.0f;
  for (int ci = 0; ci < 32; ++ci) {
    float w = conv_w[co * 96 + ci * 3 + k];  // [32,32,3]
    sv += w * gcn_w[ci];                     // gcn_w shape (1,32)
    sb += w * gcn_b[ci];
  }
  wv[idx] = sv;
  wb[idx] = sb;
}

// ---------------- epilogue: conv3 + relu + mean + linear, closed form per (b,n) ----------------
__global__ __launch_bounds__(256) void epi_k(const float* __restrict__ agg,
                                             const float* __restrict__ wv,
                                             const float* __restrict__ wb,
                                             const float* __restrict__ conv_b,
                                             const float* __restrict__ lin_w,
                                             const float* __restrict__ lin_b,
                                             float* __restrict__ out) {
  __shared__ float s_wv[96], s_wb[96], s_cb[32], s_lw[32], s_lb;
  int tid = threadIdx.x;
  if (tid < 96) { s_wv[tid] = wv[tid]; s_wb[tid] = wb[tid]; }
  if (tid < 32) { s_cb[tid] = conv_b[tid]; s_lw[tid] = lin_w[tid]; }
  if (tid == 0) s_lb = lin_b[0];
  __syncthreads();

  int n = blockIdx.x * 256 + tid;
  if (n >= N_NODES) return;
  const float4* ap = (const float4*)(agg + (size_t)n * BT);

#pragma unroll
  for (int b = 0; b < 4; ++b) {
    float4 q0 = ap[b * 3], q1 = ap[b * 3 + 1], q2 = ap[b * 3 + 2];
    float a[14];  // a[0], a[13] are the zero pads; all indices compile-time
    a[0] = 0.0f; a[13] = 0.0f;
    a[1] = q0.x; a[2] = q0.y; a[3] = q0.z; a[4] = q0.w;
    a[5] = q1.x; a[6] = q1.y; a[7] = q1.z; a[8] = q1.w;
    a[9] = q2.x; a[10] = q2.y; a[11] = q2.z; a[12] = q2.w;

    float acc = 0.0f;
    for (int co = 0; co < 32; ++co) {
      float w0 = s_wv[3 * co], w1 = s_wv[3 * co + 1], w2 = s_wv[3 * co + 2];
      float b0 = s_wb[3 * co], b1 = s_wb[3 * co + 1], b2 = s_wb[3 * co + 2];
      float base = s_cb[co] + b1;
      float lw = s_lw[co];
      float sr = 0.0f;
#pragma unroll
      for (int t = 0; t < 12; ++t) {
        float v = base + w0 * a[t] + w1 * a[t + 1] + w2 * a[t + 2];
        if (t > 0)  v += b0;   // bias only where the conv window overlaps valid h
        if (t < 11) v += b2;
        sr += fmaxf(v, 0.0f);
      }
      acc = fmaf(lw, sr, acc);
    }
    out[b * N_NODES + n] = s_lb + acc * (1.0f / 12.0f);
  }
}

extern "C" void kernel_launch(void* const* d_in, const int* in_sizes, int n_in,
                              void* d_out, int out_size, void* d_ws, size_t ws_size,
                              hipStream_t stream) {
  const float* x_seq  = (const float*)d_in[0];
  const int*   ei     = (const int*)d_in[1];   // [2, E] int32 per harness contract
  const float* ew     = (const float*)d_in[2];
  const float* gcn_w  = (const float*)d_in[3];
  const float* gcn_b  = (const float*)d_in[4];
  const float* conv_w = (const float*)d_in[5];
  const float* conv_b = (const float*)d_in[6];
  const float* lin_w  = (const float*)d_in[7];
  const float* lin_b  = (const float*)d_in[8];
  float* out = (float*)d_out;

  char* ws = (char*)d_ws;
  size_t off = 0;
  auto alloc = [&](size_t bytes) -> void* {
    void* p = ws + off;
    off += (bytes + 511) & ~(size_t)511;
    return p;
  };
  // fixed allocations first
  float* dinv = (float*)alloc((size_t)N_NODES * 4);
  int*   cnt  = (int*)alloc((size_t)N_NODES * 4);
  float* wv   = (float*)alloc(96 * 4);
  float* wb   = (float*)alloc(96 * 4);
  int*   sc   = (int*)alloc((size_t)NBINS * 4);
  int2*  ell  = (int2*)alloc((size_t)N_NODES * CAP * 8);   // 32 MB

  // staging takes the rest; xs/agg alias onto it (staging dead after build_k)
  size_t remain = (ws_size > off) ? (ws_size - off) : 0;
  int scap = (int)(remain / ((size_t)NBINS * 8));
  if (scap > 4096) scap = 4096;          // mean 2046, sd 45 -> 4096 is +45 sigma
  if (scap < 3072) scap = 3072;          // floor: +22 sigma AND >= xs+agg alias size
  int2* staged = (int2*)alloc((size_t)NBINS * scap * 8);
  float* xs  = (float*)staged;                                   // 9.6 MB
  float* agg = (float*)((char*)staged + (size_t)N_NODES * BT * 4); // next 9.6 MB

  const int nblk = (N_NODES + 255) / 256;
  const int sblk = (N_EDGES + ECHUNK - 1) / ECHUNK;
  const int wblk = (N_NODES * 64 + 255) / 256;

  hipLaunchKernelGGL(init_k, dim3(1), dim3(1024), 0, stream, sc);
  hipLaunchKernelGGL(stage_k, dim3(sblk), dim3(256), 0, stream, ei, ew, sc, staged, scap);
  hipLaunchKernelGGL(build_k, dim3(NBINS), dim3(256), 0, stream, staged, sc, ell, cnt, dinv, scap);
  hipLaunchKernelGGL(transpose_k, dim3(nblk), dim3(256), 0, stream, x_seq, dinv, xs);
  hipLaunchKernelGGL(spmm_k, dim3(wblk), dim3(256), 0, stream, xs, ell, cnt, dinv, agg);
  hipLaunchKernelGGL(coeff_k, dim3(1), dim3(128), 0, stream, conv_w, gcn_w, gcn_b, wv, wb);
  hipLaunchKernelGGL(epi_k, dim3(nblk), dim3(256), 0, stream, agg, wv, wb, conv_b, lin_w, lin_b, out);
}

// Round 5
// 212.098 us; speedup vs baseline: 1.6756x; 1.0420x over previous
//
#include <hip/hip_runtime.h>
#include <math.h>

#define N_NODES 50000
#define N_EDGES 1600000
#define BT 48            // B*T columns
#define CAP 80           // ELL capacity (degree ~ Poisson(32))
#define BINSZ 64         // nodes per bin
#define NBINS 782        // ceil(50000/64)
#define ECHUNK 4096      // edges per stage block
#define SBLOCK 1024      // stage block threads (16 waves)

// ---------------- init: stage counters = 0 ----------------
__global__ __launch_bounds__(1024) void init_k(int* __restrict__ sc) {
  int i = threadIdx.x;
  if (i < NBINS) sc[i] = 0;
}

// ---------------- Phase A: bin edges into per-bin staging (dense appends) ----------------
__global__ __launch_bounds__(SBLOCK) void stage_k(const int* __restrict__ ei,
                                                  const float* __restrict__ ew,
                                                  int* __restrict__ stage_cnt,
                                                  int2* __restrict__ staged,
                                                  int scap) {
  __shared__ int hist[NBINS];
  __shared__ int ptr[NBINS];
  int t = threadIdx.x;
  for (int b = t; b < NBINS; b += SBLOCK) hist[b] = 0;
  __syncthreads();

  int e0 = blockIdx.x * ECHUNK;
  int ne = min(ECHUNK, N_EDGES - e0);

  for (int k = t; k < ne; k += SBLOCK) {              // pass 1: histogram (dst only)
    int d = ei[N_EDGES + e0 + k];
    atomicAdd(&hist[d >> 6], 1);
  }
  __syncthreads();
  for (int b = t; b < NBINS; b += SBLOCK) {           // reserve contiguous runs
    int h = hist[b];
    ptr[b] = h ? atomicAdd(&stage_cnt[b], h) : 0;
  }
  __syncthreads();
  for (int k = t; k < ne; k += SBLOCK) {              // pass 2: append
    int e = e0 + k;
    int s = ei[e];
    int d = ei[N_EDGES + e];
    float w = ew[e];
    int b = d >> 6;
    int p = atomicAdd(&ptr[b], 1);
    if (p < scap)
      staged[(size_t)b * scap + p] = make_int2(s | ((d & 63) << 16), __float_as_int(w));
  }
}

// ---------------- Phase B: per-bin ELL build in LDS + deg/dinv + dense write-out ----------------
__global__ __launch_bounds__(256) void build_k(const int2* __restrict__ staged,
                                               const int* __restrict__ stage_cnt,
                                               int2* __restrict__ ell,
                                               int* __restrict__ cnt,
                                               float* __restrict__ dinv,
                                               int scap) {
  __shared__ int2 rows[BINSZ][CAP];   // 40 KB
  __shared__ int rcnt[BINSZ];
  int t = threadIdx.x, b = blockIdx.x;
  if (t < BINSZ) rcnt[t] = 0;
  __syncthreads();

  int ne = min(stage_cnt[b], scap);
  const int2* sp = staged + (size_t)b * scap;
  for (int k = t; k < ne; k += 256) {
    int2 m = sp[k];
    int dloc = (m.x >> 16) & 63;
    int src  = m.x & 0xffff;
    int slot = atomicAdd(&rcnt[dloc], 1);
    if (slot < CAP) rows[dloc][slot] = make_int2(src, m.y);
  }
  __syncthreads();

  int base = b * BINSZ;
  if (t < BINSZ) {                                    // deg -> dinv, cnt
    int n = base + t;
    if (n < N_NODES) {
      int c = min(rcnt[t], CAP);
      float s = 0.0f;
      for (int i = 0; i < c; ++i) s += __int_as_float(rows[t][i].y);
      cnt[n] = c;
      dinv[n] = 1.0f / sqrtf(1.0f + s);               // self-loop weight 1
    }
  }
  __syncthreads();

  int r = t & 63, st = t >> 6;                        // 4 threads per row
  int n = base + r;
  if (n < N_NODES) {
    int c = min(rcnt[r], CAP);
    int2* dst = ell + (size_t)n * CAP;
    for (int i = st; i < c; i += 4) dst[i] = rows[r][i];
  }
}

// ---- transpose+scale: x_seq [BT,N] -> xs [N,BT], xs = dinv[n]*x ----
__global__ __launch_bounds__(256) void transpose_k(const float* __restrict__ x,
                                                   const float* __restrict__ dinv,
                                                   float* __restrict__ xs) {
  int n = blockIdx.x * 256 + threadIdx.x;
  if (n >= N_NODES) return;
  float dn = dinv[n];
  float tmp[BT];
#pragma unroll
  for (int bt = 0; bt < BT; ++bt) tmp[bt] = dn * x[(size_t)bt * N_NODES + n];
  float4* dst = (float4*)(xs + (size_t)n * BT);
#pragma unroll
  for (int j = 0; j < BT / 4; ++j)
    dst[j] = make_float4(tmp[4 * j], tmp[4 * j + 1], tmp[4 * j + 2], tmp[4 * j + 3]);
}

// ---------------- SpMM: wave per node, metadata in registers, 8 gathers in flight ----------------
// agg[n,c] = dinv[n] * ( sum_e w_e * xs[src_e, c] + xs[n, c] )
__global__ __launch_bounds__(256) void spmm_k(const float* __restrict__ xs,
                                              const int2* __restrict__ ell,
                                              const int* __restrict__ cnt,
                                              const float* __restrict__ dinv,
                                              float* __restrict__ agg) {
  int lane = threadIdx.x & 63;
  int n = (blockIdx.x * 256 + threadIdx.x) >> 6;
  if (n >= N_NODES) return;
  int col = (lane < BT) ? lane : (BT - 1);            // dup col 47: no extra lines
  const int2* pp = ell + (size_t)n * CAP;
  int c = __builtin_amdgcn_readfirstlane(cnt[n]);
  int2 m = pp[lane];                                  // 64 edges' metadata in one coalesced load
  float acc = 0.0f;
  int cm = (c < 64) ? c : 64;

  int e = 0;
  for (; e + 8 <= cm; e += 8) {                       // broadcast via readlane (register-only)
    int   s0 = __builtin_amdgcn_readlane(m.x, e + 0);
    int   s1 = __builtin_amdgcn_readlane(m.x, e + 1);
    int   s2 = __builtin_amdgcn_readlane(m.x, e + 2);
    int   s3 = __builtin_amdgcn_readlane(m.x, e + 3);
    int   s4 = __builtin_amdgcn_readlane(m.x, e + 4);
    int   s5 = __builtin_amdgcn_readlane(m.x, e + 5);
    int   s6 = __builtin_amdgcn_readlane(m.x, e + 6);
    int   s7 = __builtin_amdgcn_readlane(m.x, e + 7);
    float w0 = __int_as_float(__builtin_amdgcn_readlane(m.y, e + 0));
    float w1 = __int_as_float(__builtin_amdgcn_readlane(m.y, e + 1));
    float w2 = __int_as_float(__builtin_amdgcn_readlane(m.y, e + 2));
    float w3 = __int_as_float(__builtin_amdgcn_readlane(m.y, e + 3));
    float w4 = __int_as_float(__builtin_amdgcn_readlane(m.y, e + 4));
    float w5 = __int_as_float(__builtin_amdgcn_readlane(m.y, e + 5));
    float w6 = __int_as_float(__builtin_amdgcn_readlane(m.y, e + 6));
    float w7 = __int_as_float(__builtin_amdgcn_readlane(m.y, e + 7));
    float x0 = xs[(size_t)s0 * BT + col];
    float x1 = xs[(size_t)s1 * BT + col];
    float x2 = xs[(size_t)s2 * BT + col];
    float x3 = xs[(size_t)s3 * BT + col];
    float x4 = xs[(size_t)s4 * BT + col];
    float x5 = xs[(size_t)s5 * BT + col];
    float x6 = xs[(size_t)s6 * BT + col];
    float x7 = xs[(size_t)s7 * BT + col];
    acc = fmaf(w0, x0, acc); acc = fmaf(w1, x1, acc);
    acc = fmaf(w2, x2, acc); acc = fmaf(w3, x3, acc);
    acc = fmaf(w4, x4, acc); acc = fmaf(w5, x5, acc);
    acc = fmaf(w6, x6, acc); acc = fmaf(w7, x7, acc);
  }
  for (; e < cm; ++e) {
    int   s = __builtin_amdgcn_readlane(m.x, e);
    float w = __int_as_float(__builtin_amdgcn_readlane(m.y, e));
    acc = fmaf(w, xs[(size_t)s * BT + col], acc);
  }
  for (; e < c; ++e) {                                // rare c>64 tail: meta from memory
    int2 q = pp[e];
    int   s = __builtin_amdgcn_readfirstlane(q.x);
    float w = __int_as_float(__builtin_amdgcn_readfirstlane(q.y));
    acc = fmaf(w, xs[(size_t)s * BT + col], acc);
  }

  if (lane < BT) {
    float dn = dinv[n];
    float r = dn * (acc + xs[(size_t)n * BT + col]);  // self loop: dn*xs_n = dn^2*x_n
    __builtin_nontemporal_store(r, &agg[(size_t)n * BT + col]);
  }
}

// ---------------- fold conv_w through the (rank-1) GCN weight ----------------
__global__ void coeff_k(const float* __restrict__ conv_w, const float* __restrict__ gcn_w,
                        const float* __restrict__ gcn_b, float* __restrict__ wv,
                        float* __restrict__ wb) {
  int idx = threadIdx.x;
  if (idx >= 96) return;
  int co = idx / 3, k = idx % 3;
  float sv = 0.0f, sb = 0.0f;
  for (int ci = 0; ci < 32; ++ci) {
    float w = conv_w[co * 96 + ci * 3 + k];  // [32,32,3]
    sv += w * gcn_w[ci];                     // gcn_w shape (1,32)
    sb += w * gcn_b[ci];
  }
  wv[idx] = sv;
  wb[idx] = sb;
}

// ---------------- epilogue: conv3 + relu + mean + linear, closed form per (b,n) ----------------
__global__ __launch_bounds__(256) void epi_k(const float* __restrict__ agg,
                                             const float* __restrict__ wv,
                                             const float* __restrict__ wb,
                                             const float* __restrict__ conv_b,
                                             const float* __restrict__ lin_w,
                                             const float* __restrict__ lin_b,
                                             float* __restrict__ out) {
  __shared__ float s_wv[96], s_wb[96], s_cb[32], s_lw[32], s_lb;
  int tid = threadIdx.x;
  if (tid < 96) { s_wv[tid] = wv[tid]; s_wb[tid] = wb[tid]; }
  if (tid < 32) { s_cb[tid] = conv_b[tid]; s_lw[tid] = lin_w[tid]; }
  if (tid == 0) s_lb = lin_b[0];
  __syncthreads();

  int n = blockIdx.x * 256 + tid;
  if (n >= N_NODES) return;
  const float4* ap = (const float4*)(agg + (size_t)n * BT);

#pragma unroll
  for (int b = 0; b < 4; ++b) {
    float4 q0 = ap[b * 3], q1 = ap[b * 3 + 1], q2 = ap[b * 3 + 2];
    float a[14];  // a[0], a[13] are the zero pads; all indices compile-time
    a[0] = 0.0f; a[13] = 0.0f;
    a[1] = q0.x; a[2] = q0.y; a[3] = q0.z; a[4] = q0.w;
    a[5] = q1.x; a[6] = q1.y; a[7] = q1.z; a[8] = q1.w;
    a[9] = q2.x; a[10] = q2.y; a[11] = q2.z; a[12] = q2.w;

    float acc = 0.0f;
    for (int co = 0; co < 32; ++co) {
      float w0 = s_wv[3 * co], w1 = s_wv[3 * co + 1], w2 = s_wv[3 * co + 2];
      float b0 = s_wb[3 * co], b1 = s_wb[3 * co + 1], b2 = s_wb[3 * co + 2];
      float base = s_cb[co] + b1;
      float lw = s_lw[co];
      float sr = 0.0f;
#pragma unroll
      for (int t = 0; t < 12; ++t) {
        float v = base + w0 * a[t] + w1 * a[t + 1] + w2 * a[t + 2];
        if (t > 0)  v += b0;   // bias only where the conv window overlaps valid h
        if (t < 11) v += b2;
        sr += fmaxf(v, 0.0f);
      }
      acc = fmaf(lw, sr, acc);
    }
    out[b * N_NODES + n] = s_lb + acc * (1.0f / 12.0f);
  }
}

extern "C" void kernel_launch(void* const* d_in, const int* in_sizes, int n_in,
                              void* d_out, int out_size, void* d_ws, size_t ws_size,
                              hipStream_t stream) {
  const float* x_seq  = (const float*)d_in[0];
  const int*   ei     = (const int*)d_in[1];   // [2, E] int32 per harness contract
  const float* ew     = (const float*)d_in[2];
  const float* gcn_w  = (const float*)d_in[3];
  const float* gcn_b  = (const float*)d_in[4];
  const float* conv_w = (const float*)d_in[5];
  const float* conv_b = (const float*)d_in[6];
  const float* lin_w  = (const float*)d_in[7];
  const float* lin_b  = (const float*)d_in[8];
  float* out = (float*)d_out;

  char* ws = (char*)d_ws;
  size_t off = 0;
  auto alloc = [&](size_t bytes) -> void* {
    void* p = ws + off;
    off += (bytes + 511) & ~(size_t)511;
    return p;
  };
  // fixed allocations first
  float* dinv = (float*)alloc((size_t)N_NODES * 4);
  int*   cnt  = (int*)alloc((size_t)N_NODES * 4);
  float* wv   = (float*)alloc(96 * 4);
  float* wb   = (float*)alloc(96 * 4);
  int*   sc   = (int*)alloc((size_t)NBINS * 4);
  int2*  ell  = (int2*)alloc((size_t)N_NODES * CAP * 8);   // 32 MB

  // staging takes the rest; xs/agg alias onto it (staging dead after build_k)
  size_t remain = (ws_size > off) ? (ws_size - off) : 0;
  int scap = (int)(remain / ((size_t)NBINS * 8));
  if (scap > 4096) scap = 4096;          // mean 2046, sd 45 -> 4096 is +45 sigma
  if (scap < 3072) scap = 3072;          // floor: +22 sigma AND >= xs+agg alias size
  int2* staged = (int2*)alloc((size_t)NBINS * scap * 8);
  float* xs  = (float*)staged;                                   // 9.6 MB
  float* agg = (float*)((char*)staged + (size_t)N_NODES * BT * 4); // next 9.6 MB

  const int nblk = (N_NODES + 255) / 256;
  const int sblk = (N_EDGES + ECHUNK - 1) / ECHUNK;
  const int wblk = (N_NODES * 64 + 255) / 256;

  hipLaunchKernelGGL(init_k, dim3(1), dim3(1024), 0, stream, sc);
  hipLaunchKernelGGL(stage_k, dim3(sblk), dim3(SBLOCK), 0, stream, ei, ew, sc, staged, scap);
  hipLaunchKernelGGL(build_k, dim3(NBINS), dim3(256), 0, stream, staged, sc, ell, cnt, dinv, scap);
  hipLaunchKernelGGL(transpose_k, dim3(nblk), dim3(256), 0, stream, x_seq, dinv, xs);
  hipLaunchKernelGGL(spmm_k, dim3(wblk), dim3(256), 0, stream, xs, ell, cnt, dinv, agg);
  hipLaunchKernelGGL(coeff_k, dim3(1), dim3(128), 0, stream, conv_w, gcn_w, gcn_b, wv, wb);
  hipLaunchKernelGGL(epi_k, dim3(nblk), dim3(256), 0, stream, agg, wv, wb, conv_b, lin_w, lin_b, out);
}

// Round 6
// 188.675 us; speedup vs baseline: 1.8836x; 1.1241x over previous
//
#include <hip/hip_runtime.h>
#include <hip/hip_fp16.h>
#include <math.h>

#define N_NODES 50000
#define N_EDGES 1600000
#define BT 48            // B*T columns
#define CAP 80           // ELL capacity (degree ~ Poisson(32))
#define BINSZ 64         // nodes per bin
#define NBINS 782        // ceil(50000/64)
#define ECHUNK 4096      // edges per stage block
#define SBLOCK 1024      // stage block threads (16 waves)

// ---------------- Phase A: bin edges into per-bin staging (dense appends) ----------------
__global__ __launch_bounds__(SBLOCK) void stage_k(const int* __restrict__ ei,
                                                  const float* __restrict__ ew,
                                                  int* __restrict__ stage_cnt,
                                                  int2* __restrict__ staged,
                                                  int scap) {
  __shared__ int hist[NBINS];
  __shared__ int ptr[NBINS];
  int t = threadIdx.x;
  for (int b = t; b < NBINS; b += SBLOCK) hist[b] = 0;
  __syncthreads();

  int e0 = blockIdx.x * ECHUNK;
  int ne = min(ECHUNK, N_EDGES - e0);

  for (int k = t; k < ne; k += SBLOCK) {              // pass 1: histogram (dst only)
    int d = ei[N_EDGES + e0 + k];
    atomicAdd(&hist[d >> 6], 1);
  }
  __syncthreads();
  for (int b = t; b < NBINS; b += SBLOCK) {           // reserve contiguous runs
    int h = hist[b];
    ptr[b] = h ? atomicAdd(&stage_cnt[b], h) : 0;
  }
  __syncthreads();
  for (int k = t; k < ne; k += SBLOCK) {              // pass 2: append
    int e = e0 + k;
    int s = ei[e];
    int d = ei[N_EDGES + e];
    float w = ew[e];
    int b = d >> 6;
    int p = atomicAdd(&ptr[b], 1);
    if (p < scap)
      staged[(size_t)b * scap + p] = make_int2(s | ((d & 63) << 16), __float_as_int(w));
  }
}

// ---------------- Phase B: per-bin ELL build in LDS + deg/dinv + dense write-out ----------------
__global__ __launch_bounds__(256) void build_k(const int2* __restrict__ staged,
                                               const int* __restrict__ stage_cnt,
                                               int2* __restrict__ ell,
                                               int* __restrict__ cnt,
                                               float* __restrict__ dinv,
                                               int scap) {
  __shared__ int2 rows[BINSZ][CAP];   // 40 KB
  __shared__ int rcnt[BINSZ];
  int t = threadIdx.x, b = blockIdx.x;
  if (t < BINSZ) rcnt[t] = 0;
  __syncthreads();

  int ne = min(stage_cnt[b], scap);
  const int2* sp = staged + (size_t)b * scap;
  for (int k = t; k < ne; k += 256) {
    int2 m = sp[k];
    int dloc = (m.x >> 16) & 63;
    int src  = m.x & 0xffff;
    int slot = atomicAdd(&rcnt[dloc], 1);
    if (slot < CAP) rows[dloc][slot] = make_int2(src, m.y);
  }
  __syncthreads();

  int base = b * BINSZ;
  if (t < BINSZ) {                                    // deg -> dinv, cnt
    int n = base + t;
    if (n < N_NODES) {
      int c = min(rcnt[t], CAP);
      float s = 0.0f;
      for (int i = 0; i < c; ++i) s += __int_as_float(rows[t][i].y);
      cnt[n] = c;
      dinv[n] = 1.0f / sqrtf(1.0f + s);               // self-loop weight 1
    }
  }
  __syncthreads();

  int r = t & 63, st = t >> 6;                        // 4 threads per row
  int n = base + r;
  if (n < N_NODES) {
    int c = min(rcnt[r], CAP);
    int2* dst = ell + (size_t)n * CAP;
    for (int i = st; i < c; i += 4) dst[i] = rows[r][i];
  }
}

// ---- transpose+scale+cast: x_seq [BT,N] -> xs [N,BT] fp16, xs = dinv[n]*x ----
__global__ __launch_bounds__(256) void transpose_k(const float* __restrict__ x,
                                                   const float* __restrict__ dinv,
                                                   __half* __restrict__ xs) {
  int n = blockIdx.x * 256 + threadIdx.x;
  if (n >= N_NODES) return;
  float dn = dinv[n];
  __half2 h2[BT / 2];
#pragma unroll
  for (int j = 0; j < BT / 2; ++j) {
    float a = dn * x[(size_t)(2 * j) * N_NODES + n];      // coalesced per bt-plane
    float b = dn * x[(size_t)(2 * j + 1) * N_NODES + n];
    h2[j] = __floats2half2_rn(a, b);
  }
  float4* dst = (float4*)(xs + (size_t)n * BT);           // 96 B, 16B-aligned
  const float4* srcp = (const float4*)h2;
#pragma unroll
  for (int j = 0; j < 6; ++j) dst[j] = srcp[j];
}

// ---- fold conv_w through the (rank-1) GCN weight ----
__global__ void coeff_k(const float* __restrict__ conv_w, const float* __restrict__ gcn_w,
                        const float* __restrict__ gcn_b, float* __restrict__ wv,
                        float* __restrict__ wb) {
  int idx = threadIdx.x;
  if (idx >= 96) return;
  int co = idx / 3, k = idx % 3;
  float sv = 0.0f, sb = 0.0f;
  for (int ci = 0; ci < 32; ++ci) {
    float w = conv_w[co * 96 + ci * 3 + k];  // [32,32,3]
    sv += w * gcn_w[ci];                     // gcn_w shape (1,32)
    sb += w * gcn_b[ci];
  }
  wv[idx] = sv;
  wb[idx] = sb;
}

// ---------------- SpMM + fused epilogue: wave per node ----------------
// agg[n,c] = dinv[n]*(sum_e w_e*xs[src_e,c] + xs[n,c]); then conv3+relu+mean+linear in-wave.
__global__ __launch_bounds__(256) void spmm_epi_k(const __half* __restrict__ xs,
                                                  const int2* __restrict__ ell,
                                                  const int* __restrict__ cnt,
                                                  const float* __restrict__ dinv,
                                                  const float* __restrict__ wv,
                                                  const float* __restrict__ wb,
                                                  const float* __restrict__ conv_b,
                                                  const float* __restrict__ lin_w,
                                                  const float* __restrict__ lin_b,
                                                  float* __restrict__ out) {
  __shared__ float s_wv[96], s_wb[96], s_cb[32], s_lw[32];
  __shared__ float s_lb;
  __shared__ float sAgg[4][BT];
  int tid = threadIdx.x;
  if (tid < 96) { s_wv[tid] = wv[tid]; s_wb[tid] = wb[tid]; }
  if (tid < 32) { s_cb[tid] = conv_b[tid]; s_lw[tid] = lin_w[tid]; }
  if (tid == 0) s_lb = lin_b[0];
  __syncthreads();

  int lane = tid & 63;
  int wid  = tid >> 6;
  int n = (blockIdx.x * 256 + tid) >> 6;               // grid is exact: no tail
  int col = (lane < BT) ? lane : (BT - 1);
  const int2* pp = ell + (size_t)n * CAP;
  int c = __builtin_amdgcn_readfirstlane(cnt[n]);
  int2 m = pp[lane];                                   // 64 edges' metadata, one coalesced load
  float acc = 0.0f;
  int cm = (c < 64) ? c : 64;

  int e = 0;
  for (; e + 16 <= cm; e += 16) {                      // 16 gathers in flight
    float xv[16], wgt[16];
#pragma unroll
    for (int k = 0; k < 16; ++k) {
      int s  = __builtin_amdgcn_readlane(m.x, e + k);
      wgt[k] = __int_as_float(__builtin_amdgcn_readlane(m.y, e + k));
      xv[k]  = __half2float(xs[(size_t)s * BT + col]);
    }
#pragma unroll
    for (int k = 0; k < 16; ++k) acc = fmaf(wgt[k], xv[k], acc);
  }
  for (; e + 8 <= cm; e += 8) {
    float xv[8], wgt[8];
#pragma unroll
    for (int k = 0; k < 8; ++k) {
      int s  = __builtin_amdgcn_readlane(m.x, e + k);
      wgt[k] = __int_as_float(__builtin_amdgcn_readlane(m.y, e + k));
      xv[k]  = __half2float(xs[(size_t)s * BT + col]);
    }
#pragma unroll
    for (int k = 0; k < 8; ++k) acc = fmaf(wgt[k], xv[k], acc);
  }
  for (; e < cm; ++e) {
    int   s = __builtin_amdgcn_readlane(m.x, e);
    float w = __int_as_float(__builtin_amdgcn_readlane(m.y, e));
    acc = fmaf(w, __half2float(xs[(size_t)s * BT + col]), acc);
  }
  for (; e < c; ++e) {                                 // rare c>64 tail: meta from memory
    int2 q = pp[e];
    int   s = __builtin_amdgcn_readfirstlane(q.x);
    float w = __int_as_float(__builtin_amdgcn_readfirstlane(q.y));
    acc = fmaf(w, __half2float(xs[(size_t)s * BT + col]), acc);
  }

  float dn = dinv[n];
  float xsn = __half2float(xs[(size_t)n * BT + col]);
  if (lane < BT) sAgg[wid][col] = dn * (acc + xsn);    // self loop: dn*xs_n = dn^2*x_n
  // same-wave LDS write->read; compiler inserts lgkmcnt wait

  // ---- fused epilogue: lane -> (b = lane>>4, co = lane&15 and +16) ----
  int b = lane >> 4;
  float a[14];
  a[0] = 0.0f; a[13] = 0.0f;
#pragma unroll
  for (int t = 0; t < 12; ++t) a[t + 1] = sAgg[wid][b * 12 + t];  // broadcast within group

  float part = 0.0f;
#pragma unroll
  for (int cc = 0; cc < 2; ++cc) {
    int co = (lane & 15) + cc * 16;
    float w0 = s_wv[3 * co], w1 = s_wv[3 * co + 1], w2 = s_wv[3 * co + 2];
    float b0 = s_wb[3 * co], b1 = s_wb[3 * co + 1], b2 = s_wb[3 * co + 2];
    float base = s_cb[co] + b1;
    float lw = s_lw[co];
    float sr = 0.0f;
#pragma unroll
    for (int t = 0; t < 12; ++t) {
      float v = base + w0 * a[t] + w1 * a[t + 1] + w2 * a[t + 2];
      if (t > 0)  v += b0;   // conv window overlap with valid h
      if (t < 11) v += b2;
      sr += fmaxf(v, 0.0f);
    }
    part = fmaf(lw, sr, part);
  }
  part += __shfl_xor(part, 1, 64);                     // reduce 16 lanes = all 32 co
  part += __shfl_xor(part, 2, 64);
  part += __shfl_xor(part, 4, 64);
  part += __shfl_xor(part, 8, 64);
  if ((lane & 15) == 0)
    out[(size_t)b * N_NODES + n] = s_lb + part * (1.0f / 12.0f);
}

extern "C" void kernel_launch(void* const* d_in, const int* in_sizes, int n_in,
                              void* d_out, int out_size, void* d_ws, size_t ws_size,
                              hipStream_t stream) {
  const float* x_seq  = (const float*)d_in[0];
  const int*   ei     = (const int*)d_in[1];   // [2, E] int32 per harness contract
  const float* ew     = (const float*)d_in[2];
  const float* gcn_w  = (const float*)d_in[3];
  const float* gcn_b  = (const float*)d_in[4];
  const float* conv_w = (const float*)d_in[5];
  const float* conv_b = (const float*)d_in[6];
  const float* lin_w  = (const float*)d_in[7];
  const float* lin_b  = (const float*)d_in[8];
  float* out = (float*)d_out;

  char* ws = (char*)d_ws;
  size_t off = 0;
  auto alloc = [&](size_t bytes) -> void* {
    void* p = ws + off;
    off += (bytes + 511) & ~(size_t)511;
    return p;
  };
  // fixed allocations first
  float* dinv = (float*)alloc((size_t)N_NODES * 4);
  int*   cnt  = (int*)alloc((size_t)N_NODES * 4);
  float* wv   = (float*)alloc(96 * 4);
  float* wb   = (float*)alloc(96 * 4);
  int*   sc   = (int*)alloc((size_t)NBINS * 4);
  int2*  ell  = (int2*)alloc((size_t)N_NODES * CAP * 8);   // 32 MB

  // staging takes the rest; xs aliases onto it (staging dead after build_k)
  size_t remain = (ws_size > off) ? (ws_size - off) : 0;
  int scap = (int)(remain / ((size_t)NBINS * 8));
  if (scap > 4096) scap = 4096;          // mean 2046, sd 45 -> 4096 is +45 sigma
  if (scap < 3072) scap = 3072;          // floor: +22 sigma AND >= xs alias size
  int2* staged = (int2*)alloc((size_t)NBINS * scap * 8);
  __half* xs = (__half*)staged;          // 4.8 MB, alive only after build_k

  const int nblk = (N_NODES + 255) / 256;
  const int sblk = (N_EDGES + ECHUNK - 1) / ECHUNK;
  const int wblk = (N_NODES * 64) / 256;               // exact: 12500

  hipMemsetAsync(sc, 0, (size_t)NBINS * 4, stream);
  hipLaunchKernelGGL(stage_k, dim3(sblk), dim3(SBLOCK), 0, stream, ei, ew, sc, staged, scap);
  hipLaunchKernelGGL(build_k, dim3(NBINS), dim3(256), 0, stream, staged, sc, ell, cnt, dinv, scap);
  hipLaunchKernelGGL(transpose_k, dim3(nblk), dim3(256), 0, stream, x_seq, dinv, xs);
  hipLaunchKernelGGL(coeff_k, dim3(1), dim3(128), 0, stream, conv_w, gcn_w, gcn_b, wv, wb);
  hipLaunchKernelGGL(spmm_epi_k, dim3(wblk), dim3(256), 0, stream,
                     xs, ell, cnt, dinv, wv, wb, conv_b, lin_w, lin_b, out);
}